// Round 1
// baseline (13819.858 us; speedup 1.0000x reference)
//
#include <hip/hip_runtime.h>
#include <math.h>

// Problem constants
#define B_  2048
#define S_  128
#define H_  512
#define K_  16
#define NSTEP 63   // T-4

constexpr int BM = 64, BN = 64, BK = 32;

// Generic tiled f32 GEMM: C_pre = A(MxK) @ W(KxN) + bias_eff
//   bias_eff[col] = bias[col] (+ t*Wrow0[col] if HAS_T), t = ts[3+step]
// EPI 0: C[row*ldc+col] = (RELU? max(0,v) : v)
// EPI 1: fused dW-contraction: gp[row,s] = sum_k v(row, s*16+k) * dW[row,k]*sqrt(dt)
//        C = gp (B x 128); optional C2 = Ybase + gp
// EPI 2: final update: C[row,col] = Ybase + v*dt + 0.5*(gpA+gpB)
template<bool HAS_T, bool RELU, int EPI>
__global__ __launch_bounds__(256)
void gemm_k(const float* __restrict__ A, int lda,
            const float* __restrict__ W, int ldw,
            const float* __restrict__ Wrow0,
            const float* __restrict__ bias,
            const float* __restrict__ ts, int step,
            int K,
            const float* __restrict__ Ybase,
            const float* __restrict__ dWp,
            const float* __restrict__ gpA,
            const float* __restrict__ gpB,
            float* __restrict__ C, int ldc,
            float* __restrict__ C2)
{
    __shared__ float As[BM][BK + 4];   // +4 pad keeps float4 alignment, breaks bank stride
    __shared__ float Ws[BK][BN];

    const int tid = threadIdx.x;
    const int tx = tid & 15, ty = tid >> 4;
    const int rowBase = blockIdx.x * BM;
    const int colBase = blockIdx.y * BN;

    float acc[4][4] = {};

    const int ar = tid >> 3;          // 0..31
    const int ac = (tid & 7) << 2;    // 0..28
    const int wr = tid >> 4;          // 0..15
    const int wc = (tid & 15) << 2;   // 0..60

    for (int k0 = 0; k0 < K; k0 += BK) {
        *(float4*)&As[ar][ac]       = *(const float4*)&A[(size_t)(rowBase + ar) * lda + k0 + ac];
        *(float4*)&As[ar + 32][ac]  = *(const float4*)&A[(size_t)(rowBase + ar + 32) * lda + k0 + ac];
        *(float4*)&Ws[wr][wc]       = *(const float4*)&W[(size_t)(k0 + wr) * ldw + colBase + wc];
        *(float4*)&Ws[wr + 16][wc]  = *(const float4*)&W[(size_t)(k0 + wr + 16) * ldw + colBase + wc];
        __syncthreads();
#pragma unroll
        for (int kk = 0; kk < BK; ++kk) {
            float a[4], w[4];
#pragma unroll
            for (int i = 0; i < 4; ++i) a[i] = As[ty + 16 * i][kk];
#pragma unroll
            for (int j = 0; j < 4; ++j) w[j] = Ws[kk][tx + 16 * j];
#pragma unroll
            for (int i = 0; i < 4; ++i)
#pragma unroll
                for (int j = 0; j < 4; ++j)
                    acc[i][j] += a[i] * w[j];
        }
        __syncthreads();
    }

    // effective bias (folds the time column)
    float be[4];
#pragma unroll
    for (int j = 0; j < 4; ++j) {
        int col = colBase + tx + 16 * j;
        float b = bias ? bias[col] : 0.f;
        if (HAS_T) b += ts[3 + step] * Wrow0[col];
        be[j] = b;
    }

    if (EPI == 0) {
#pragma unroll
        for (int i = 0; i < 4; ++i) {
            int row = rowBase + ty + 16 * i;
#pragma unroll
            for (int j = 0; j < 4; ++j) {
                int col = colBase + tx + 16 * j;
                float v = acc[i][j] + be[j];
                if (RELU) v = fmaxf(v, 0.f);
                C[(size_t)row * ldc + col] = v;
            }
        }
    } else if (EPI == 1) {
        float dt = ts[4 + step] - ts[3 + step];
        float sq = sqrtf(dt);
#pragma unroll
        for (int i = 0; i < 4; ++i) {
            int row = rowBase + ty + 16 * i;
            float dwv = dWp[row * K_ + tx] * sq;   // k = tx
#pragma unroll
            for (int j = 0; j < 4; ++j) {
                float m = (acc[i][j] + be[j]) * dwv;
                m += __shfl_xor(m, 1);
                m += __shfl_xor(m, 2);
                m += __shfl_xor(m, 4);
                m += __shfl_xor(m, 8);
                if (tx == 0) {
                    int s = (colBase >> 4) + j;    // col = s*16 + k
                    size_t idx = (size_t)row * S_ + s;
                    C[idx] = m;
                    if (C2) C2[idx] = Ybase[idx] + m;
                }
            }
        }
    } else {  // EPI == 2 : y1 = y + drift*dt + 0.5*(gp+gp')
        float dt = ts[4 + step] - ts[3 + step];
#pragma unroll
        for (int i = 0; i < 4; ++i) {
            int row = rowBase + ty + 16 * i;
#pragma unroll
            for (int j = 0; j < 4; ++j) {
                int col = colBase + tx + 16 * j;
                float v = acc[i][j] + be[j];
                size_t idx = (size_t)row * S_ + col;
                C[idx] = Ybase[idx] + v * dt + 0.5f * (gpA[idx] + gpB[idx]);
            }
        }
    }
}

// y0 = relu(x @ enc_w1 + enc_b1) @ enc_w2 + enc_b2 ; x: (B,3)
__global__ __launch_bounds__(128)
void encoder_k(const float* __restrict__ x,
               const float* __restrict__ w1, const float* __restrict__ b1,
               const float* __restrict__ w2, const float* __restrict__ b2,
               float* __restrict__ y0)
{
    int b = blockIdx.x;
    __shared__ float h[H_];
    int tid = threadIdx.x;
    float x0 = x[b * 3 + 0], x1 = x[b * 3 + 1], x2 = x[b * 3 + 2];
    for (int i = tid; i < H_; i += 128) {
        float v = x0 * w1[i] + x1 * w1[H_ + i] + x2 * w1[2 * H_ + i] + b1[i];
        h[i] = fmaxf(v, 0.f);
    }
    __syncthreads();
    float acc = b2[tid];
    for (int k = 0; k < H_; ++k) acc += h[k] * w2[k * S_ + tid];
    y0[(size_t)b * S_ + tid] = acc;
}

extern "C" void kernel_launch(void* const* d_in, const int* in_sizes, int n_in,
                              void* d_out, int out_size, void* d_ws, size_t ws_size,
                              hipStream_t stream)
{
    const float* ts     = (const float*)d_in[0];
    const float* x      = (const float*)d_in[1];
    const float* enc_w1 = (const float*)d_in[2];
    const float* enc_b1 = (const float*)d_in[3];
    const float* enc_w2 = (const float*)d_in[4];
    const float* enc_b2 = (const float*)d_in[5];
    const float* f_w1   = (const float*)d_in[6];
    const float* f_b1   = (const float*)d_in[7];
    const float* f_w2   = (const float*)d_in[8];
    const float* f_b2   = (const float*)d_in[9];
    const float* f_w3   = (const float*)d_in[10];
    const float* f_b3   = (const float*)d_in[11];
    const float* g_w1   = (const float*)d_in[12];
    const float* g_b1   = (const float*)d_in[13];
    const float* g_w2   = (const float*)d_in[14];
    const float* g_b2   = (const float*)d_in[15];
    const float* dW     = (const float*)d_in[16];

    float* out = (float*)d_out;
    float* ws  = (float*)d_ws;

    float* h_a  = ws;                       // B*H = 1048576
    float* h_b  = ws + 1048576;             // B*H
    float* gp   = ws + 2097152;             // B*S = 262144
    float* gp2  = ws + 2359296;             // B*S
    float* ytmp = ws + 2621440;             // B*S   (total 11.5 MB)

    // y0 -> out slice 0
    encoder_k<<<B_, 128, 0, stream>>>(x, enc_w1, enc_b1, enc_w2, enc_b2, out);

    const dim3 gLin(B_ / BM, H_ / BN);      // 32 x 8
    const dim3 gBig(B_ / BM, (S_ * K_) / BN); // 32 x 32
    const dim3 gOut(B_ / BM, S_ / BN);      // 32 x 2

    for (int step = 0; step < NSTEP; ++step) {
        const float* y  = out + (size_t)step * B_ * S_;
        float*       y1 = out + (size_t)(step + 1) * B_ * S_;
        const float* dWs = dW + (size_t)step * B_ * K_;

        // h_a = relu([t,y] @ g_w1 + g_b1)
        gemm_k<true, true, 0><<<gLin, 256, 0, stream>>>(
            y, S_, g_w1 + H_, H_, g_w1, g_b1, ts, step, S_,
            nullptr, nullptr, nullptr, nullptr, h_a, H_, nullptr);

        // gp = einsum(h_a@g_w2+g_b2, dW*sqrt(dt)) ; ytmp = y + gp
        gemm_k<false, false, 1><<<gBig, 256, 0, stream>>>(
            h_a, H_, g_w2, S_ * K_, nullptr, g_b2, ts, step, H_,
            y, dWs, nullptr, nullptr, gp, S_, ytmp);

        // h_a = relu([t,ytmp] @ g_w1 + g_b1)
        gemm_k<true, true, 0><<<gLin, 256, 0, stream>>>(
            ytmp, S_, g_w1 + H_, H_, g_w1, g_b1, ts, step, S_,
            nullptr, nullptr, nullptr, nullptr, h_a, H_, nullptr);

        // gp2 = einsum(h_a@g_w2+g_b2, dW*sqrt(dt))
        gemm_k<false, false, 1><<<gBig, 256, 0, stream>>>(
            h_a, H_, g_w2, S_ * K_, nullptr, g_b2, ts, step, H_,
            nullptr, dWs, nullptr, nullptr, gp2, S_, nullptr);

        // h_a = relu([t,y] @ f_w1 + f_b1)
        gemm_k<true, true, 0><<<gLin, 256, 0, stream>>>(
            y, S_, f_w1 + H_, H_, f_w1, f_b1, ts, step, S_,
            nullptr, nullptr, nullptr, nullptr, h_a, H_, nullptr);

        // h_b = relu(h_a @ f_w2 + f_b2)
        gemm_k<false, true, 0><<<gLin, 256, 0, stream>>>(
            h_a, H_, f_w2, H_, nullptr, f_b2, ts, step, H_,
            nullptr, nullptr, nullptr, nullptr, h_b, H_, nullptr);

        // y1 = y + (h_b @ f_w3 + f_b3)*dt + 0.5*(gp+gp2)
        gemm_k<false, false, 2><<<gOut, 256, 0, stream>>>(
            h_b, H_, f_w3, S_, nullptr, f_b3, ts, step, H_,
            y, nullptr, gp, gp2, y1, S_, nullptr);
    }
}

// Round 2
// 7383.208 us; speedup vs baseline: 1.8718x; 1.8718x over previous
//
#include <hip/hip_runtime.h>
#include <hip/hip_bf16.h>
#include <math.h>

#define B_  2048
#define S_  128
#define H_  512
#define K_  16
#define NSTEP 63

typedef __bf16 bf16x8 __attribute__((ext_vector_type(8)));
typedef float  f32x4  __attribute__((ext_vector_type(4)));
typedef unsigned short u16x8 __attribute__((ext_vector_type(8)));

static __device__ __forceinline__ void f2b2(float v, unsigned short& hi, unsigned short& lo)
{
    __hip_bfloat16 h = __float2bfloat16(v);
    float r = v - __bfloat162float(h);
    __hip_bfloat16 l = __float2bfloat16(r);
    hi = __builtin_bit_cast(unsigned short, h);
    lo = __builtin_bit_cast(unsigned short, l);
}

// Core: C += A(MxK) @ W(KxN), A split hi/lo row-major [M][lda], W split pre-transposed [N][K].
// 3-MFMA split product: ahi*bhi + ahi*blo + alo*bhi (f32 accum).
// Block = 256 threads = 4 waves arranged (BM/WM)x(BN/WN); each wave WM x WN.
template<int BM,int BN,int WM,int WN>
__device__ __forceinline__ void gemm_core(
    const unsigned short* __restrict__ Ahi, const unsigned short* __restrict__ Alo, int lda,
    const unsigned short* __restrict__ Whi, const unsigned short* __restrict__ Wlo,
    int K, int rowBase, int colBase,
    f32x4 (&acc)[WM/16][WN/16])
{
    constexpr int MI = WM/16, NJ = WN/16, NWC = BN/WN;
    __shared__ unsigned short Als[2][4][BM][8];   // [plane][kg][row][8] : 16B rows -> 2-way bank alias (free)
    __shared__ unsigned short Bls[2][4][BN][8];

    const int tid = threadIdx.x;
    const int l   = tid & 63;
    const int wid = tid >> 6;
    const int wr  = wid / NWC, wc = wid % NWC;
    const int r16 = l & 15, kg = l >> 4;

    for (int k0 = 0; k0 < K; k0 += 32) {
#pragma unroll
        for (int e = 0; e < BM*4; e += 256) {
            int idx = e + tid;
            int row = idx % BM, g = idx / BM;
            size_t off = (size_t)(rowBase + row) * lda + k0 + g*8;
            *(int4*)&Als[0][g][row][0] = *(const int4*)&Ahi[off];
            *(int4*)&Als[1][g][row][0] = *(const int4*)&Alo[off];
        }
#pragma unroll
        for (int e = 0; e < BN*4; e += 256) {
            int idx = e + tid;
            int row = idx % BN, g = idx / BN;
            size_t off = (size_t)(colBase + row) * K + k0 + g*8;
            *(int4*)&Bls[0][g][row][0] = *(const int4*)&Whi[off];
            *(int4*)&Bls[1][g][row][0] = *(const int4*)&Wlo[off];
        }
        __syncthreads();

        bf16x8 ah[MI], al[MI], bh[NJ], bl[NJ];
#pragma unroll
        for (int i = 0; i < MI; ++i) {
            ah[i] = __builtin_bit_cast(bf16x8, *(const u16x8*)&Als[0][kg][wr*WM + i*16 + r16][0]);
            al[i] = __builtin_bit_cast(bf16x8, *(const u16x8*)&Als[1][kg][wr*WM + i*16 + r16][0]);
        }
#pragma unroll
        for (int j = 0; j < NJ; ++j) {
            bh[j] = __builtin_bit_cast(bf16x8, *(const u16x8*)&Bls[0][kg][wc*WN + j*16 + r16][0]);
            bl[j] = __builtin_bit_cast(bf16x8, *(const u16x8*)&Bls[1][kg][wc*WN + j*16 + r16][0]);
        }
#pragma unroll
        for (int i = 0; i < MI; ++i)
#pragma unroll
            for (int j = 0; j < NJ; ++j) {
                acc[i][j] = __builtin_amdgcn_mfma_f32_16x16x32_bf16(ah[i], bh[j], acc[i][j], 0, 0, 0);
                acc[i][j] = __builtin_amdgcn_mfma_f32_16x16x32_bf16(ah[i], bl[j], acc[i][j], 0, 0, 0);
                acc[i][j] = __builtin_amdgcn_mfma_f32_16x16x32_bf16(al[i], bh[j], acc[i][j], 0, 0, 0);
            }
        __syncthreads();
    }
}

// ---------- phase kernels ----------
// C/D frag layout (m89-verified): col = lane&15, row = (lane>>4)*4 + reg.

// K1: HA = relu([t,y] @ [g_w1|f_w1]) -> (2048 x 1024) bf16 hi/lo
__global__ __launch_bounds__(256) void k1_phase(
    const unsigned short* __restrict__ ycH, const unsigned short* __restrict__ ycL,
    const unsigned short* __restrict__ w1tH, const unsigned short* __restrict__ w1tL,
    const float* __restrict__ g_w1, const float* __restrict__ f_w1,
    const float* __restrict__ g_b1, const float* __restrict__ f_b1,
    const float* __restrict__ ts, int step,
    unsigned short* __restrict__ HAh, unsigned short* __restrict__ HAl)
{
    constexpr int BM=64, BN=64, WM=32, WN=32, MI=2, NJ=2, NWC=BN/WN;
    f32x4 acc[MI][NJ] = {};
    const int rowBase = blockIdx.x*BM, colBase = blockIdx.y*BN;
    gemm_core<BM,BN,WM,WN>(ycH, ycL, S_, w1tH, w1tL, S_, rowBase, colBase, acc);

    const int tid=threadIdx.x, l=tid&63, wid=tid>>6;
    const int wr=wid/NWC, wc=wid%NWC, r16=l&15, rg=l>>4;
    const float t = ts[3+step];
#pragma unroll
    for (int j=0;j<NJ;++j){
        int colj = colBase + wc*WN + j*16 + r16;
        float be = (colj < 512) ? (g_b1[colj] + t*g_w1[colj])
                                : (f_b1[colj-512] + t*f_w1[colj-512]);
#pragma unroll
        for (int i=0;i<MI;++i)
#pragma unroll
            for (int reg=0;reg<4;++reg){
                int row = rowBase + wr*WM + i*16 + rg*4 + reg;
                float v = fmaxf(acc[i][j][reg] + be, 0.f);
                unsigned short h,lo; f2b2(v,h,lo);
                size_t o = (size_t)row*1024 + colj;
                HAh[o]=h; HAl[o]=lo;
            }
    }
}

// K2: section g (by<16): gp = contract(HA_g @ g_w2 + g_b2, dW*sqrt(dt)); ytmp = y+gp (hi/lo)
//     section f (by>=16): HB = relu(HA_f @ f_w2 + f_b2) (hi/lo)
__global__ __launch_bounds__(256) void k2_phase(
    const unsigned short* __restrict__ HAh, const unsigned short* __restrict__ HAl,
    const unsigned short* __restrict__ gw2H, const unsigned short* __restrict__ gw2L,
    const unsigned short* __restrict__ fw2H, const unsigned short* __restrict__ fw2L,
    const float* __restrict__ g_b2, const float* __restrict__ f_b2,
    const float* __restrict__ y,
    const float* __restrict__ dWs,
    const float* __restrict__ ts, int step,
    float* __restrict__ gp,
    unsigned short* __restrict__ ytH, unsigned short* __restrict__ ytL,
    unsigned short* __restrict__ HBh, unsigned short* __restrict__ HBl)
{
    constexpr int BM=64, BN=128, WM=32, WN=64, MI=2, NJ=4, NWC=BN/WN;
    f32x4 acc[MI][NJ] = {};
    const int rowBase = blockIdx.x*BM;
    const int by = blockIdx.y;
    const int tid=threadIdx.x, l=tid&63, wid=tid>>6;
    const int wr=wid/NWC, wc=wid%NWC, r16=l&15, rg=l>>4;

    if (by < 16) {
        const int colBase = by*BN;
        gemm_core<BM,BN,WM,WN>(HAh, HAl, 1024, gw2H, gw2L, H_, rowBase, colBase, acc);
        const float dt = ts[4+step]-ts[3+step], sq = sqrtf(dt);
#pragma unroll
        for (int i=0;i<MI;++i)
#pragma unroll
            for (int reg=0;reg<4;++reg){
                int row = rowBase + wr*WM + i*16 + rg*4 + reg;
                float dwv = dWs[row*K_ + r16] * sq;
#pragma unroll
                for (int j=0;j<NJ;++j){
                    int colj = colBase + wc*WN + j*16;
                    float m = (acc[i][j][reg] + g_b2[colj + r16]) * dwv;
                    m += __shfl_xor(m,1); m += __shfl_xor(m,2);
                    m += __shfl_xor(m,4); m += __shfl_xor(m,8);
                    if (r16 == 0){
                        int idx = row*S_ + (colj>>4);
                        gp[idx] = m;
                        unsigned short h,lo; f2b2(y[idx] + m, h, lo);
                        ytH[idx]=h; ytL[idx]=lo;
                    }
                }
            }
    } else {
        const int colBase = (by-16)*BN;
        gemm_core<BM,BN,WM,WN>(HAh + 512, HAl + 512, 1024, fw2H, fw2L, H_, rowBase, colBase, acc);
#pragma unroll
        for (int j=0;j<NJ;++j){
            int colj = colBase + wc*WN + j*16 + r16;
            float be = f_b2[colj];
#pragma unroll
            for (int i=0;i<MI;++i)
#pragma unroll
                for (int reg=0;reg<4;++reg){
                    int row = rowBase + wr*WM + i*16 + rg*4 + reg;
                    float v = fmaxf(acc[i][j][reg] + be, 0.f);
                    unsigned short h,lo; f2b2(v,h,lo);
                    size_t o = (size_t)row*512 + colj;
                    HBh[o]=h; HBl[o]=lo;
                }
        }
    }
}

// K3: section a (by<8): HA2 = relu([t,ytmp] @ g_w1 + g_b1) (hi/lo, ld 512)
//     section b (by>=8): drift = HB @ f_w3 + f_b3 (f32, 2048x128)
__global__ __launch_bounds__(256) void k3_phase(
    const unsigned short* __restrict__ ytH, const unsigned short* __restrict__ ytL,
    const unsigned short* __restrict__ w1tH, const unsigned short* __restrict__ w1tL,
    const float* __restrict__ g_b1, const float* __restrict__ g_w1,
    const unsigned short* __restrict__ HBh, const unsigned short* __restrict__ HBl,
    const unsigned short* __restrict__ fw3H, const unsigned short* __restrict__ fw3L,
    const float* __restrict__ f_b3,
    const float* __restrict__ ts, int step,
    unsigned short* __restrict__ HA2h, unsigned short* __restrict__ HA2l,
    float* __restrict__ drift)
{
    constexpr int BM=64, BN=64, WM=32, WN=32, MI=2, NJ=2, NWC=BN/WN;
    f32x4 acc[MI][NJ] = {};
    const int rowBase = blockIdx.x*BM;
    const int by = blockIdx.y;
    const int tid=threadIdx.x, l=tid&63, wid=tid>>6;
    const int wr=wid/NWC, wc=wid%NWC, r16=l&15, rg=l>>4;

    if (by < 8) {
        const int colBase = by*BN;
        gemm_core<BM,BN,WM,WN>(ytH, ytL, S_, w1tH, w1tL, S_, rowBase, colBase, acc);
        const float t = ts[3+step];
#pragma unroll
        for (int j=0;j<NJ;++j){
            int colj = colBase + wc*WN + j*16 + r16;
            float be = g_b1[colj] + t*g_w1[colj];
#pragma unroll
            for (int i=0;i<MI;++i)
#pragma unroll
                for (int reg=0;reg<4;++reg){
                    int row = rowBase + wr*WM + i*16 + rg*4 + reg;
                    float v = fmaxf(acc[i][j][reg] + be, 0.f);
                    unsigned short h,lo; f2b2(v,h,lo);
                    size_t o = (size_t)row*512 + colj;
                    HA2h[o]=h; HA2l[o]=lo;
                }
        }
    } else {
        const int colBase = (by-8)*BN;
        gemm_core<BM,BN,WM,WN>(HBh, HBl, H_, fw3H, fw3L, H_, rowBase, colBase, acc);
#pragma unroll
        for (int j=0;j<NJ;++j){
            int colj = colBase + wc*WN + j*16 + r16;
            float be = f_b3[colj];
#pragma unroll
            for (int i=0;i<MI;++i)
#pragma unroll
                for (int reg=0;reg<4;++reg){
                    int row = rowBase + wr*WM + i*16 + rg*4 + reg;
                    drift[row*S_ + colj] = acc[i][j][reg] + be;
                }
        }
    }
}

// K4: gp2 contraction + final update: y1 = y + drift*dt + 0.5*(gp+gp2); write y1 f32 + ycur hi/lo
__global__ __launch_bounds__(256) void k4_phase(
    const unsigned short* __restrict__ HA2h, const unsigned short* __restrict__ HA2l,
    const unsigned short* __restrict__ gw2H, const unsigned short* __restrict__ gw2L,
    const float* __restrict__ g_b2,
    const float* __restrict__ y,
    const float* __restrict__ gp,
    const float* __restrict__ drift,
    const float* __restrict__ dWs,
    const float* __restrict__ ts, int step,
    float* __restrict__ y1,
    unsigned short* __restrict__ ycH, unsigned short* __restrict__ ycL)
{
    constexpr int BM=64, BN=128, WM=32, WN=64, MI=2, NJ=4, NWC=BN/WN;
    f32x4 acc[MI][NJ] = {};
    const int rowBase = blockIdx.x*BM;
    const int colBase = blockIdx.y*BN;
    gemm_core<BM,BN,WM,WN>(HA2h, HA2l, H_, gw2H, gw2L, H_, rowBase, colBase, acc);

    const int tid=threadIdx.x, l=tid&63, wid=tid>>6;
    const int wr=wid/NWC, wc=wid%NWC, r16=l&15, rg=l>>4;
    const float dt = ts[4+step]-ts[3+step], sq = sqrtf(dt);
#pragma unroll
    for (int i=0;i<MI;++i)
#pragma unroll
        for (int reg=0;reg<4;++reg){
            int row = rowBase + wr*WM + i*16 + rg*4 + reg;
            float dwv = dWs[row*K_ + r16] * sq;
#pragma unroll
            for (int j=0;j<NJ;++j){
                int colj = colBase + wc*WN + j*16;
                float m = (acc[i][j][reg] + g_b2[colj + r16]) * dwv;
                m += __shfl_xor(m,1); m += __shfl_xor(m,2);
                m += __shfl_xor(m,4); m += __shfl_xor(m,8);
                if (r16 == 0){
                    int idx = row*S_ + (colj>>4);
                    float v1 = y[idx] + drift[idx]*dt + 0.5f*(gp[idx] + m);
                    y1[idx] = v1;
                    unsigned short h,lo; f2b2(v1,h,lo);
                    ycH[idx]=h; ycL[idx]=lo;
                }
            }
        }
}

// transpose + split-cast: in (rows=[rowOff..rowOff+Kd) x N f32) -> out [N][Kd] bf16 hi/lo
__global__ __launch_bounds__(256) void tcast_k(
    const float* __restrict__ in, int rowOff, int Kd, int N,
    unsigned short* __restrict__ outH, unsigned short* __restrict__ outL)
{
    __shared__ float tl[32][33];
    const int kb = blockIdx.x*32, nb = blockIdx.y*32;
    const int tx = threadIdx.x, ty = threadIdx.y;
    for (int r = ty; r < 32; r += 8)
        tl[r][tx] = in[(size_t)(rowOff + kb + r)*N + nb + tx];
    __syncthreads();
    for (int r = ty; r < 32; r += 8){
        unsigned short h,lo; f2b2(tl[tx][r],h,lo);
        size_t o = (size_t)(nb + r)*Kd + kb + tx;
        outH[o]=h; outL[o]=lo;
    }
}

// y0 = relu(x @ enc_w1 + enc_b1) @ enc_w2 + enc_b2 ; also emit ycur hi/lo
__global__ __launch_bounds__(128) void encoder_k(
    const float* __restrict__ x,
    const float* __restrict__ w1, const float* __restrict__ b1,
    const float* __restrict__ w2, const float* __restrict__ b2,
    float* __restrict__ y0,
    unsigned short* __restrict__ ycH, unsigned short* __restrict__ ycL)
{
    int b = blockIdx.x;
    __shared__ float h[H_];
    int tid = threadIdx.x;
    float x0 = x[b*3+0], x1 = x[b*3+1], x2 = x[b*3+2];
    for (int i = tid; i < H_; i += 128)
        h[i] = fmaxf(x0*w1[i] + x1*w1[H_+i] + x2*w1[2*H_+i] + b1[i], 0.f);
    __syncthreads();
    float acc = b2[tid];
    for (int k = 0; k < H_; ++k) acc += h[k]*w2[k*S_+tid];
    size_t o = (size_t)b*S_ + tid;
    y0[o] = acc;
    unsigned short hh,ll; f2b2(acc,hh,ll);
    ycH[o]=hh; ycL[o]=ll;
}

extern "C" void kernel_launch(void* const* d_in, const int* in_sizes, int n_in,
                              void* d_out, int out_size, void* d_ws, size_t ws_size,
                              hipStream_t stream)
{
    const float* ts     = (const float*)d_in[0];
    const float* x      = (const float*)d_in[1];
    const float* enc_w1 = (const float*)d_in[2];
    const float* enc_b1 = (const float*)d_in[3];
    const float* enc_w2 = (const float*)d_in[4];
    const float* enc_b2 = (const float*)d_in[5];
    const float* f_w1   = (const float*)d_in[6];
    const float* f_b1   = (const float*)d_in[7];
    const float* f_w2   = (const float*)d_in[8];
    const float* f_b2   = (const float*)d_in[9];
    const float* f_w3   = (const float*)d_in[10];
    const float* f_b3   = (const float*)d_in[11];
    const float* g_w1   = (const float*)d_in[12];
    const float* g_b1   = (const float*)d_in[13];
    const float* g_w2   = (const float*)d_in[14];
    const float* g_b2   = (const float*)d_in[15];
    const float* dW     = (const float*)d_in[16];

    float* out = (float*)d_out;
    unsigned short* w = (unsigned short*)d_ws;

    // ws layout (ushort elements)
    unsigned short* w1tH  = w;                      // 1024*128
    unsigned short* w1tL  = w1tH  + 1024*128;
    unsigned short* gw2H  = w1tL  + 1024*128;       // 2048*512
    unsigned short* gw2L  = gw2H  + 2048*512;
    unsigned short* fw2H  = gw2L  + 2048*512;       // 512*512
    unsigned short* fw2L  = fw2H  + 512*512;
    unsigned short* fw3H  = fw2L  + 512*512;        // 128*512
    unsigned short* fw3L  = fw3H  + 128*512;
    unsigned short* HAh   = fw3L  + 128*512;        // 2048*1024
    unsigned short* HAl   = HAh   + 2048*1024;
    unsigned short* HBh   = HAl   + 2048*1024;      // 2048*512
    unsigned short* HBl   = HBh   + 2048*512;
    unsigned short* ytH   = HBl   + 2048*512;       // 2048*128
    unsigned short* ytL   = ytH   + 2048*128;
    unsigned short* ycH   = ytL   + 2048*128;       // 2048*128
    unsigned short* ycL   = ycH   + 2048*128;
    float* gp    = (float*)(ycL + 2048*128);        // 2048*128 f32
    float* drift = gp + 2048*128;                   // 2048*128 f32
    // HA2 aliases HA (HA dead after K2)
    unsigned short* HA2h = HAh;
    unsigned short* HA2l = HAl;

    dim3 tb(32,8);
    tcast_k<<<dim3(4,16),  tb, 0, stream>>>(g_w1, 1, 128, 512,  w1tH,          w1tL);
    tcast_k<<<dim3(4,16),  tb, 0, stream>>>(f_w1, 1, 128, 512,  w1tH+512*128,  w1tL+512*128);
    tcast_k<<<dim3(16,16), tb, 0, stream>>>(f_w2, 0, 512, 512,  fw2H,          fw2L);
    tcast_k<<<dim3(16,4),  tb, 0, stream>>>(f_w3, 0, 512, 128,  fw3H,          fw3L);
    tcast_k<<<dim3(16,64), tb, 0, stream>>>(g_w2, 0, 512, 2048, gw2H,          gw2L);

    encoder_k<<<B_, 128, 0, stream>>>(x, enc_w1, enc_b1, enc_w2, enc_b2, out, ycH, ycL);

    for (int step = 0; step < NSTEP; ++step) {
        const float* y   = out + (size_t)step * B_ * S_;
        float*       y1  = out + (size_t)(step+1) * B_ * S_;
        const float* dWs = dW  + (size_t)step * B_ * K_;

        k1_phase<<<dim3(32,16), 256, 0, stream>>>(ycH, ycL, w1tH, w1tL, g_w1, f_w1,
                                                  g_b1, f_b1, ts, step, HAh, HAl);
        k2_phase<<<dim3(32,20), 256, 0, stream>>>(HAh, HAl, gw2H, gw2L, fw2H, fw2L,
                                                  g_b2, f_b2, y, dWs, ts, step,
                                                  gp, ytH, ytL, HBh, HBl);
        k3_phase<<<dim3(32,10), 256, 0, stream>>>(ytH, ytL, w1tH, w1tL, g_b1, g_w1,
                                                  HBh, HBl, fw3H, fw3L, f_b3, ts, step,
                                                  HA2h, HA2l, drift);
        k4_phase<<<dim3(32,16), 256, 0, stream>>>(HA2h, HA2l, gw2H, gw2L, g_b2,
                                                  y, gp, drift, dWs, ts, step,
                                                  y1, ycH, ycL);
    }
}

// Round 3
// 7321.815 us; speedup vs baseline: 1.8875x; 1.0084x over previous
//
#include <hip/hip_runtime.h>
#include <hip/hip_bf16.h>
#include <math.h>

#define B_  2048
#define S_  128
#define H_  512
#define K_  16
#define NSTEP 63

typedef __bf16 bf16x8 __attribute__((ext_vector_type(8)));
typedef float  f32x4  __attribute__((ext_vector_type(4)));
typedef unsigned short u16x8 __attribute__((ext_vector_type(8)));

static __device__ __forceinline__ void f2b2(float v, unsigned short& hi, unsigned short& lo)
{
    __hip_bfloat16 h = __float2bfloat16(v);
    float r = v - __bfloat162float(h);
    __hip_bfloat16 l = __float2bfloat16(r);
    hi = __builtin_bit_cast(unsigned short, h);
    lo = __builtin_bit_cast(unsigned short, l);
}

// async global->LDS, 16B per lane; LDS dest = wave-uniform base + lane*16
static __device__ __forceinline__ void gl16(const unsigned short* g, unsigned short* l)
{
    __builtin_amdgcn_global_load_lds(
        (const __attribute__((address_space(1))) unsigned int*)g,
        (__attribute__((address_space(3))) unsigned int*)l, 16, 0, 0);
}

// Core: C += A(MxK) @ W(KxN); A split hi/lo row-major [M][lda]; W split pre-transposed [N][K].
// 3-MFMA split: ahi*bhi + ahi*blo + alo*bhi (f32 accum).
// LDS planes [Ahi|Alo|Bhi|Blo], each chunked [kg][row][8] (16B chunks, linear in load order:
// chunk c -> row=c%R, kg=c/R; frag reads are 256B-contiguous per 16-lane group -> 2-way, free).
template<int BM,int BN,int BK,int WM,int WN>
__device__ __forceinline__ void gemm_core(
    unsigned short* lds,
    const unsigned short* __restrict__ Ahi, const unsigned short* __restrict__ Alo, int lda,
    const unsigned short* __restrict__ Whi, const unsigned short* __restrict__ Wlo, int K,
    int rowBase, int colBase, f32x4 (&acc)[WM/16][WN/16])
{
    constexpr int MI = WM/16, NJ = WN/16, NWC = BN/WN;
    constexpr int NT = (BM/WM)*(BN/WN)*64;
    constexpr int ACH = BM*BK/8, BCH = BN*BK/8;
    unsigned short* Ah = lds;
    unsigned short* Al = lds + (size_t)ACH*8;
    unsigned short* Bh = lds + (size_t)2*ACH*8;
    unsigned short* Bl = lds + (size_t)2*ACH*8 + (size_t)BCH*8;

    const int tid = threadIdx.x, lane = tid & 63;
    const int wid = tid >> 6;
    const int wr = wid / NWC, wc = wid % NWC;
    const int r16 = lane & 15, kg = lane >> 4;
    const int ubase = tid & ~63;   // wave-uniform chunk base

    for (int k0 = 0; k0 < K; k0 += BK) {
#pragma unroll
        for (int c0 = 0; c0 < ACH; c0 += NT) {
            int c = c0 + tid;
            int row = c % BM, g = c / BM;
            size_t off = (size_t)(rowBase + row) * lda + k0 + g*8;
            gl16(Ahi + off, Ah + (size_t)(c0 + ubase)*8);
            gl16(Alo + off, Al + (size_t)(c0 + ubase)*8);
        }
#pragma unroll
        for (int c0 = 0; c0 < BCH; c0 += NT) {
            int c = c0 + tid;
            int row = c % BN, g = c / BN;
            size_t off = (size_t)(colBase + row) * K + k0 + g*8;
            gl16(Whi + off, Bh + (size_t)(c0 + ubase)*8);
            gl16(Wlo + off, Bl + (size_t)(c0 + ubase)*8);
        }
        __syncthreads();
#pragma unroll
        for (int kk = 0; kk < BK/32; ++kk) {
            bf16x8 ah[MI], al[MI], bh[NJ], bl[NJ];
#pragma unroll
            for (int i = 0; i < MI; ++i) {
                int idx = (kk*4 + kg)*BM + wr*WM + i*16 + r16;
                ah[i] = __builtin_bit_cast(bf16x8, *(const u16x8*)(Ah + (size_t)idx*8));
                al[i] = __builtin_bit_cast(bf16x8, *(const u16x8*)(Al + (size_t)idx*8));
            }
#pragma unroll
            for (int j = 0; j < NJ; ++j) {
                int idx = (kk*4 + kg)*BN + wc*WN + j*16 + r16;
                bh[j] = __builtin_bit_cast(bf16x8, *(const u16x8*)(Bh + (size_t)idx*8));
                bl[j] = __builtin_bit_cast(bf16x8, *(const u16x8*)(Bl + (size_t)idx*8));
            }
#pragma unroll
            for (int i = 0; i < MI; ++i)
#pragma unroll
                for (int j = 0; j < NJ; ++j) {
                    acc[i][j] = __builtin_amdgcn_mfma_f32_16x16x32_bf16(ah[i], bh[j], acc[i][j], 0, 0, 0);
                    acc[i][j] = __builtin_amdgcn_mfma_f32_16x16x32_bf16(ah[i], bl[j], acc[i][j], 0, 0, 0);
                    acc[i][j] = __builtin_amdgcn_mfma_f32_16x16x32_bf16(al[i], bh[j], acc[i][j], 0, 0, 0);
                }
        }
        __syncthreads();
    }
}

// ---------- phase kernels ----------
// C/D frag: col = lane&15, row = (lane>>4)*4 + reg.

// K1: HA = relu([t,y] @ [g_w1|f_w1]) -> (2048 x 1024) hi/lo. BM=64 BN=128.
__global__ __launch_bounds__(256) void k1_phase(
    const unsigned short* __restrict__ ycH, const unsigned short* __restrict__ ycL,
    const unsigned short* __restrict__ w1tH, const unsigned short* __restrict__ w1tL,
    const float* __restrict__ g_w1, const float* __restrict__ f_w1,
    const float* __restrict__ g_b1, const float* __restrict__ f_b1,
    const float* __restrict__ ts, int step,
    unsigned short* __restrict__ HAh, unsigned short* __restrict__ HAl)
{
    constexpr int BM=64, BN=128, WM=32, WN=64, MI=2, NJ=4, NWC=BN/WN;
    __shared__ __align__(16) unsigned short lds[(BM+BN)*64*2];
    f32x4 acc[MI][NJ] = {};
    const int rowBase = blockIdx.x*BM, colBase = blockIdx.y*BN;
    gemm_core<BM,BN,64,WM,WN>(lds, ycH, ycL, S_, w1tH, w1tL, S_, rowBase, colBase, acc);

    const int tid=threadIdx.x, l=tid&63, wid=tid>>6;
    const int wr=wid/NWC, wc=wid%NWC, r16=l&15, rg=l>>4;
    const float t = ts[3+step];
#pragma unroll
    for (int j=0;j<NJ;++j){
        int colj = colBase + wc*WN + j*16 + r16;
        float be = (colj < 512) ? (g_b1[colj] + t*g_w1[colj])
                                : (f_b1[colj-512] + t*f_w1[colj-512]);
#pragma unroll
        for (int i=0;i<MI;++i)
#pragma unroll
            for (int reg=0;reg<4;++reg){
                int row = rowBase + wr*WM + i*16 + rg*4 + reg;
                float v = fmaxf(acc[i][j][reg] + be, 0.f);
                unsigned short h,lo; f2b2(v,h,lo);
                size_t o = (size_t)row*1024 + colj;
                HAh[o]=h; HAl[o]=lo;
            }
    }
}

// K2: by<16: gp = contract(HA_g @ g_w2 + g_b2, dW*sqrt(dt)); ytmp = y+gp (hi/lo)
//     by>=16: HB = relu(HA_f @ f_w2 + f_b2) (hi/lo)
__global__ __launch_bounds__(256) void k2_phase(
    const unsigned short* __restrict__ HAh, const unsigned short* __restrict__ HAl,
    const unsigned short* __restrict__ gw2H, const unsigned short* __restrict__ gw2L,
    const unsigned short* __restrict__ fw2H, const unsigned short* __restrict__ fw2L,
    const float* __restrict__ g_b2, const float* __restrict__ f_b2,
    const float* __restrict__ y,
    const float* __restrict__ dWs,
    const float* __restrict__ ts, int step,
    float* __restrict__ gp,
    unsigned short* __restrict__ ytH, unsigned short* __restrict__ ytL,
    unsigned short* __restrict__ HBh, unsigned short* __restrict__ HBl)
{
    constexpr int BM=64, BN=128, WM=32, WN=64, MI=2, NJ=4, NWC=BN/WN;
    __shared__ __align__(16) unsigned short lds[(BM+BN)*64*2];
    f32x4 acc[MI][NJ] = {};
    const int rowBase = blockIdx.x*BM;
    const int by = blockIdx.y;
    const int tid=threadIdx.x, l=tid&63, wid=tid>>6;
    const int wr=wid/NWC, wc=wid%NWC, r16=l&15, rg=l>>4;

    if (by < 16) {
        const int colBase = by*BN;
        gemm_core<BM,BN,64,WM,WN>(lds, HAh, HAl, 1024, gw2H, gw2L, H_, rowBase, colBase, acc);
        const float dt = ts[4+step]-ts[3+step], sq = sqrtf(dt);
#pragma unroll
        for (int i=0;i<MI;++i)
#pragma unroll
            for (int reg=0;reg<4;++reg){
                int row = rowBase + wr*WM + i*16 + rg*4 + reg;
                float dwv = dWs[row*K_ + r16] * sq;
#pragma unroll
                for (int j=0;j<NJ;++j){
                    int colj = colBase + wc*WN + j*16;
                    float m = (acc[i][j][reg] + g_b2[colj + r16]) * dwv;
                    m += __shfl_xor(m,1); m += __shfl_xor(m,2);
                    m += __shfl_xor(m,4); m += __shfl_xor(m,8);
                    if (r16 == 0){
                        int idx = row*S_ + (colj>>4);
                        gp[idx] = m;
                        unsigned short h,lo; f2b2(y[idx] + m, h, lo);
                        ytH[idx]=h; ytL[idx]=lo;
                    }
                }
            }
    } else {
        const int colBase = (by-16)*BN;
        gemm_core<BM,BN,64,WM,WN>(lds, HAh + 512, HAl + 512, 1024, fw2H, fw2L, H_, rowBase, colBase, acc);
#pragma unroll
        for (int j=0;j<NJ;++j){
            int colj = colBase + wc*WN + j*16 + r16;
            float be = f_b2[colj];
#pragma unroll
            for (int i=0;i<MI;++i)
#pragma unroll
                for (int reg=0;reg<4;++reg){
                    int row = rowBase + wr*WM + i*16 + rg*4 + reg;
                    float v = fmaxf(acc[i][j][reg] + be, 0.f);
                    unsigned short h,lo; f2b2(v,h,lo);
                    size_t o = (size_t)row*512 + colj;
                    HBh[o]=h; HBl[o]=lo;
                }
        }
    }
}

// K3: by<8: HA2 = relu([t,ytmp] @ g_w1 + g_b1) (hi/lo, ld 512); by>=8: drift = HB @ f_w3 + f_b3
__global__ __launch_bounds__(256) void k3_phase(
    const unsigned short* __restrict__ ytH, const unsigned short* __restrict__ ytL,
    const unsigned short* __restrict__ w1tH, const unsigned short* __restrict__ w1tL,
    const float* __restrict__ g_b1, const float* __restrict__ g_w1,
    const unsigned short* __restrict__ HBh, const unsigned short* __restrict__ HBl,
    const unsigned short* __restrict__ fw3H, const unsigned short* __restrict__ fw3L,
    const float* __restrict__ f_b3,
    const float* __restrict__ ts, int step,
    unsigned short* __restrict__ HA2h, unsigned short* __restrict__ HA2l,
    float* __restrict__ drift)
{
    constexpr int BM=64, BN=64, WM=32, WN=32, MI=2, NJ=2, NWC=BN/WN;
    __shared__ __align__(16) unsigned short lds[(BM+BN)*64*2];
    f32x4 acc[MI][NJ] = {};
    const int rowBase = blockIdx.x*BM;
    const int by = blockIdx.y;
    const int tid=threadIdx.x, l=tid&63, wid=tid>>6;
    const int wr=wid/NWC, wc=wid%NWC, r16=l&15, rg=l>>4;

    if (by < 8) {
        const int colBase = by*BN;
        gemm_core<BM,BN,64,WM,WN>(lds, ytH, ytL, S_, w1tH, w1tL, S_, rowBase, colBase, acc);
        const float t = ts[3+step];
#pragma unroll
        for (int j=0;j<NJ;++j){
            int colj = colBase + wc*WN + j*16 + r16;
            float be = g_b1[colj] + t*g_w1[colj];
#pragma unroll
            for (int i=0;i<MI;++i)
#pragma unroll
                for (int reg=0;reg<4;++reg){
                    int row = rowBase + wr*WM + i*16 + rg*4 + reg;
                    float v = fmaxf(acc[i][j][reg] + be, 0.f);
                    unsigned short h,lo; f2b2(v,h,lo);
                    size_t o = (size_t)row*512 + colj;
                    HA2h[o]=h; HA2l[o]=lo;
                }
        }
    } else {
        const int colBase = (by-8)*BN;
        gemm_core<BM,BN,64,WM,WN>(lds, HBh, HBl, H_, fw3H, fw3L, H_, rowBase, colBase, acc);
#pragma unroll
        for (int j=0;j<NJ;++j){
            int colj = colBase + wc*WN + j*16 + r16;
            float be = f_b3[colj];
#pragma unroll
            for (int i=0;i<MI;++i)
#pragma unroll
                for (int reg=0;reg<4;++reg){
                    int row = rowBase + wr*WM + i*16 + rg*4 + reg;
                    drift[row*S_ + colj] = acc[i][j][reg] + be;
                }
        }
    }
}

// K4: gp2 contraction + final update
__global__ __launch_bounds__(256) void k4_phase(
    const unsigned short* __restrict__ HA2h, const unsigned short* __restrict__ HA2l,
    const unsigned short* __restrict__ gw2H, const unsigned short* __restrict__ gw2L,
    const float* __restrict__ g_b2,
    const float* __restrict__ y,
    const float* __restrict__ gp,
    const float* __restrict__ drift,
    const float* __restrict__ dWs,
    const float* __restrict__ ts, int step,
    float* __restrict__ y1,
    unsigned short* __restrict__ ycH, unsigned short* __restrict__ ycL)
{
    constexpr int BM=64, BN=128, WM=32, WN=64, MI=2, NJ=4, NWC=BN/WN;
    __shared__ __align__(16) unsigned short lds[(BM+BN)*64*2];
    f32x4 acc[MI][NJ] = {};
    const int rowBase = blockIdx.x*BM;
    const int colBase = blockIdx.y*BN;
    gemm_core<BM,BN,64,WM,WN>(lds, HA2h, HA2l, H_, gw2H, gw2L, H_, rowBase, colBase, acc);

    const int tid=threadIdx.x, l=tid&63, wid=tid>>6;
    const int wr=wid/NWC, wc=wid%NWC, r16=l&15, rg=l>>4;
    const float dt = ts[4+step]-ts[3+step], sq = sqrtf(dt);
#pragma unroll
    for (int i=0;i<MI;++i)
#pragma unroll
        for (int reg=0;reg<4;++reg){
            int row = rowBase + wr*WM + i*16 + rg*4 + reg;
            float dwv = dWs[row*K_ + r16] * sq;
#pragma unroll
            for (int j=0;j<NJ;++j){
                int colj = colBase + wc*WN + j*16;
                float m = (acc[i][j][reg] + g_b2[colj + r16]) * dwv;
                m += __shfl_xor(m,1); m += __shfl_xor(m,2);
                m += __shfl_xor(m,4); m += __shfl_xor(m,8);
                if (r16 == 0){
                    int idx = row*S_ + (colj>>4);
                    float v1 = y[idx] + drift[idx]*dt + 0.5f*(gp[idx] + m);
                    y1[idx] = v1;
                    unsigned short h,lo; f2b2(v1,h,lo);
                    ycH[idx]=h; ycL[idx]=lo;
                }
            }
        }
}

// transpose + split-cast: in (rows=[rowOff..rowOff+Kd) x N f32) -> out [N][Kd] hi/lo
__global__ __launch_bounds__(256) void tcast_k(
    const float* __restrict__ in, int rowOff, int Kd, int N,
    unsigned short* __restrict__ outH, unsigned short* __restrict__ outL)
{
    __shared__ float tl[32][33];
    const int kb = blockIdx.x*32, nb = blockIdx.y*32;
    const int tx = threadIdx.x, ty = threadIdx.y;
    for (int r = ty; r < 32; r += 8)
        tl[r][tx] = in[(size_t)(rowOff + kb + r)*N + nb + tx];
    __syncthreads();
    for (int r = ty; r < 32; r += 8){
        unsigned short h,lo; f2b2(tl[tx][r],h,lo);
        size_t o = (size_t)(nb + r)*Kd + kb + tx;
        outH[o]=h; outL[o]=lo;
    }
}

__global__ __launch_bounds__(128) void encoder_k(
    const float* __restrict__ x,
    const float* __restrict__ w1, const float* __restrict__ b1,
    const float* __restrict__ w2, const float* __restrict__ b2,
    float* __restrict__ y0,
    unsigned short* __restrict__ ycH, unsigned short* __restrict__ ycL)
{
    int b = blockIdx.x;
    __shared__ float h[H_];
    int tid = threadIdx.x;
    float x0 = x[b*3+0], x1 = x[b*3+1], x2 = x[b*3+2];
    for (int i = tid; i < H_; i += 128)
        h[i] = fmaxf(x0*w1[i] + x1*w1[H_+i] + x2*w1[2*H_+i] + b1[i], 0.f);
    __syncthreads();
    float acc = b2[tid];
    for (int k = 0; k < H_; ++k) acc += h[k]*w2[k*S_+tid];
    size_t o = (size_t)b*S_ + tid;
    y0[o] = acc;
    unsigned short hh,ll; f2b2(acc,hh,ll);
    ycH[o]=hh; ycL[o]=ll;
}

extern "C" void kernel_launch(void* const* d_in, const int* in_sizes, int n_in,
                              void* d_out, int out_size, void* d_ws, size_t ws_size,
                              hipStream_t stream)
{
    const float* ts     = (const float*)d_in[0];
    const float* x      = (const float*)d_in[1];
    const float* enc_w1 = (const float*)d_in[2];
    const float* enc_b1 = (const float*)d_in[3];
    const float* enc_w2 = (const float*)d_in[4];
    const float* enc_b2 = (const float*)d_in[5];
    const float* f_w1   = (const float*)d_in[6];
    const float* f_b1   = (const float*)d_in[7];
    const float* f_w2   = (const float*)d_in[8];
    const float* f_b2   = (const float*)d_in[9];
    const float* f_w3   = (const float*)d_in[10];
    const float* f_b3   = (const float*)d_in[11];
    const float* g_w1   = (const float*)d_in[12];
    const float* g_b1   = (const float*)d_in[13];
    const float* g_w2   = (const float*)d_in[14];
    const float* g_b2   = (const float*)d_in[15];
    const float* dW     = (const float*)d_in[16];

    float* out = (float*)d_out;
    unsigned short* w = (unsigned short*)d_ws;

    unsigned short* w1tH  = w;                      // 1024*128
    unsigned short* w1tL  = w1tH  + 1024*128;
    unsigned short* gw2H  = w1tL  + 1024*128;       // 2048*512
    unsigned short* gw2L  = gw2H  + 2048*512;
    unsigned short* fw2H  = gw2L  + 2048*512;       // 512*512
    unsigned short* fw2L  = fw2H  + 512*512;
    unsigned short* fw3H  = fw2L  + 512*512;        // 128*512
    unsigned short* fw3L  = fw3H  + 128*512;
    unsigned short* HAh   = fw3L  + 128*512;        // 2048*1024
    unsigned short* HAl   = HAh   + 2048*1024;
    unsigned short* HBh   = HAl   + 2048*1024;      // 2048*512
    unsigned short* HBl   = HBh   + 2048*512;
    unsigned short* ytH   = HBl   + 2048*512;       // 2048*128
    unsigned short* ytL   = ytH   + 2048*128;
    unsigned short* ycH   = ytL   + 2048*128;       // 2048*128
    unsigned short* ycL   = ycH   + 2048*128;
    float* gp    = (float*)(ycL + 2048*128);        // 2048*128 f32
    float* drift = gp + 2048*128;                   // 2048*128 f32
    unsigned short* HA2h = HAh;                     // alias (HA dead after K2)
    unsigned short* HA2l = HAl;

    dim3 tb(32,8);
    tcast_k<<<dim3(4,16),  tb, 0, stream>>>(g_w1, 1, 128, 512,  w1tH,          w1tL);
    tcast_k<<<dim3(4,16),  tb, 0, stream>>>(f_w1, 1, 128, 512,  w1tH+512*128,  w1tL+512*128);
    tcast_k<<<dim3(16,16), tb, 0, stream>>>(f_w2, 0, 512, 512,  fw2H,          fw2L);
    tcast_k<<<dim3(16,4),  tb, 0, stream>>>(f_w3, 0, 512, 128,  fw3H,          fw3L);
    tcast_k<<<dim3(16,64), tb, 0, stream>>>(g_w2, 0, 512, 2048, gw2H,          gw2L);

    encoder_k<<<B_, 128, 0, stream>>>(x, enc_w1, enc_b1, enc_w2, enc_b2, out, ycH, ycL);

    for (int step = 0; step < NSTEP; ++step) {
        const float* y   = out + (size_t)step * B_ * S_;
        float*       y1  = out + (size_t)(step+1) * B_ * S_;
        const float* dWs = dW  + (size_t)step * B_ * K_;

        k1_phase<<<dim3(32,8),  256, 0, stream>>>(ycH, ycL, w1tH, w1tL, g_w1, f_w1,
                                                  g_b1, f_b1, ts, step, HAh, HAl);
        k2_phase<<<dim3(32,20), 256, 0, stream>>>(HAh, HAl, gw2H, gw2L, fw2H, fw2L,
                                                  g_b2, f_b2, y, dWs, ts, step,
                                                  gp, ytH, ytL, HBh, HBl);
        k3_phase<<<dim3(32,10), 256, 0, stream>>>(ytH, ytL, w1tH, w1tL, g_b1, g_w1,
                                                  HBh, HBl, fw3H, fw3L, f_b3, ts, step,
                                                  HA2h, HA2l, drift);
        k4_phase<<<dim3(32,16), 256, 0, stream>>>(HA2h, HA2l, gw2H, gw2L, g_b2,
                                                  y, gp, drift, dWs, ts, step,
                                                  y1, ycH, ycL);
    }
}